// Round 4
// baseline (215.029 us; speedup 1.0000x reference)
//
#include <hip/hip_runtime.h>

#define T_FULL 4096
#define D 128
#define K 1024
#define NVEC 65536           // 16*4096
#define BDT 8388608          // 16*128*4096
#define BT 128               // tokens per block
#define NBLK (NVEC / BT)     // 512 blocks
#define KT 32                // codes per staged tile
#define NIT (K / KT)         // 32 iterations
#define PLANE_B (K * D * 2)  // 262144 bytes per bf16 plane
#define TILE_B (3 * KT * D * 2)   // 24576 bytes per staged tile (3 planes)

typedef unsigned short ushort_t;
typedef __bf16 bf16x8 __attribute__((ext_vector_type(8)));
typedef float f32x4 __attribute__((ext_vector_type(4)));

// truncate f32 -> bf16 bits (exact split: x - hi(x) is exact in f32)
__device__ __forceinline__ float trunc_bf(float x, ushort_t* bits) {
  union { float f; unsigned u; } a; a.f = x;
  *bits = (ushort_t)(a.u >> 16);
  union { unsigned u; float f; } b; b.u = a.u & 0xFFFF0000u;
  return b.f;
}
__device__ __forceinline__ __bf16 bf_bits(ushort_t u) {
  union { ushort_t u; __bf16 h; } c; c.u = u; return c.h;
}

#define MFMA(a, b, c) __builtin_amdgcn_mfma_f32_16x16x32_bf16((a), (b), (c), 0, 0, 0)

#define GLOAD_LDS(g, l)                                                        \
  __builtin_amdgcn_global_load_lds(                                            \
      (const __attribute__((address_space(1))) unsigned int*)(g),              \
      (__attribute__((address_space(3))) unsigned int*)(l), 16, 0, 0)

// ---------------- prep: zero ws + ee norms + scaled (2e) 3-way bf16 split ----------------
__global__ __launch_bounds__(128) void prep_kernel(const float* __restrict__ cb,
    float* __restrict__ ee, ushort_t* __restrict__ Eh, ushort_t* __restrict__ Em,
    ushort_t* __restrict__ El, unsigned int* __restrict__ counts,
    unsigned int* __restrict__ done, float* __restrict__ loss_acc) {
  int k = blockIdx.x, d = threadIdx.x;
  if (d == 0) {
    counts[k] = 0u;
    if (k == 0) { *done = 0u; *loss_acc = 0.f; }
  }
  float e = cb[k * D + d];
  float v = e * e;
#pragma unroll
  for (int o = 32; o > 0; o >>= 1) v += __shfl_down(v, o, 64);
  __shared__ float tmp[2];
  if ((d & 63) == 0) tmp[d >> 6] = v;
  __syncthreads();
  if (d == 0) ee[k] = tmp[0] + tmp[1];

  float s = 2.0f * e;                       // fold the -2*dot scale (exact)
  ushort_t hb, mb, lb;
  float hf = trunc_bf(s, &hb);
  float r  = s - hf;
  float mf = trunc_bf(r, &mb);
  (void)trunc_bf(r - mf, &lb);
  Eh[k * D + d] = hb; Em[k * D + d] = mb; El[k * D + d] = lb;
}

// ---------------- main: A-in-regs, B dbuf in LDS, reg-epilogue, last-block fin ----------------
__global__ __launch_bounds__(256, 2) void vq_main(
    const float* __restrict__ inp, const float* __restrict__ cb,
    const float* __restrict__ ee, const ushort_t* __restrict__ Eplanes,
    unsigned int* __restrict__ counts, unsigned int* __restrict__ done,
    float* __restrict__ loss_acc, float* __restrict__ out) {
  __shared__ __align__(16) ushort_t Bs[2 * 3 * KT * D];   // 48 KB, XOR-swizzled
  __shared__ float ee_sh[K];                              // 4 KB
  __shared__ int   midx[BT];
  __shared__ float lred[4];
  __shared__ int   lastf;

  float* out_q   = out + 1;
  float* out_idx = out + 2 + BDT;

  const int tid  = threadIdx.x;
  const int lane = tid & 63;
  const int w    = tid >> 6;        // wave: owns tokens w*32..w*32+31
  const int c    = lane & 15;       // MFMA col (code) / token within 16
  const int q    = lane >> 4;       // quad
  const int b    = blockIdx.x >> 5;
  const int t0   = (blockIdx.x & 31) * BT;

  // --- per-lane staging offsets (16B-swizzled: lds slot s -> global dg = (s&15)^(code&15)) ---
  unsigned soff[6], sldsoff[6];
#pragma unroll
  for (int i = 0; i < 6; ++i) {
    int flatb = w * 384 + i * 64;          // wave-uniform slot base (0..1472)
    int p     = flatb >> 9;                // plane 0..2
    int s     = (flatb & 511) + lane;      // slot within plane (code*16 + dg')
    int code  = s >> 4;
    int dg    = (s & 15) ^ (code & 15);
    soff[i]    = (unsigned)(p * PLANE_B + code * 256 + dg * 16);
    sldsoff[i] = (unsigned)(flatb * 16);
  }
  const char* Eb = (const char*)Eplanes;

  // --- issue stage of buffer 0 (kt = 0) ---
#pragma unroll
  for (int i = 0; i < 6; ++i)
    GLOAD_LDS(Eb + soff[i], (char*)Bs + sldsoff[i]);

  // --- X -> registers, exact 3-way bf16 split, per-wave dim-chunk rotation ---
  // slot dci holds global dim-chunk dcg=(dci+w)&3 (addresses runtime, reg idx const)
  bf16x8 Ah[2][4], Am[2][4], Al[2][4];
  {
    const float* xin = inp + (size_t)b * D * T_FULL + t0 + w * 32 + c;
#pragma unroll
    for (int n = 0; n < 2; ++n)
#pragma unroll
      for (int dci = 0; dci < 4; ++dci) {
        const int dcg = (dci + w) & 3;
        bf16x8 ah, am, al;
#pragma unroll
        for (int j = 0; j < 8; ++j) {
          int d = dcg * 32 + q * 8 + j;
          float x = xin[(size_t)d * T_FULL + n * 16];
          ushort_t hb, mb, lb;
          float hf = trunc_bf(x, &hb);
          float r  = x - hf;
          float mf = trunc_bf(r, &mb);
          (void)trunc_bf(r - mf, &lb);
          ah[j] = bf_bits(hb); am[j] = bf_bits(mb); al[j] = bf_bits(lb);
        }
        Ah[n][dci] = ah; Am[n][dci] = am; Al[n][dci] = al;
      }
  }
  // --- ee -> LDS ---
#pragma unroll
  for (int i = tid; i < K; i += 256) ee_sh[i] = ee[i];
  __syncthreads();

  float bv[2][4];
  int   bi[2][4];
#pragma unroll
  for (int n = 0; n < 2; ++n)
#pragma unroll
    for (int r = 0; r < 4; ++r) { bv[n][r] = 3.4e38f; bi[n][r] = 0; }

  for (int it = 0; it < NIT; ++it) {
    const int kt = it * KT;
    const int bb = it & 1;

    // prefetch next tile into buffer bb^1 (wraps harmlessly on last iter)
    {
      const int ktn = (kt + KT) & (K - 1);
      const unsigned lb = (unsigned)((bb ^ 1) * TILE_B);
#pragma unroll
      for (int i = 0; i < 6; ++i)
        GLOAD_LDS(Eb + (size_t)ktn * 256 + soff[i], (char*)Bs + lb + sldsoff[i]);
    }

    // compute on buffer bb
    f32x4 acc[2][2];
#pragma unroll
    for (int n = 0; n < 2; ++n)
#pragma unroll
      for (int kf = 0; kf < 2; ++kf) acc[n][kf] = (f32x4){0.f, 0.f, 0.f, 0.f};

    const char* Bp = (const char*)Bs + bb * TILE_B;
#pragma unroll
    for (int dci = 0; dci < 4; ++dci) {
      const int dcg = (dci + w) & 3;
      const int sw = ((dcg * 4 + q) ^ c) * 16;       // de-swizzle
      bf16x8 Bh[2], Bm[2], Bl[2];
#pragma unroll
      for (int kf = 0; kf < 2; ++kf) {
        const int ro = (kf * 16 + c) * 256 + sw;
        Bh[kf] = *(const bf16x8*)(Bp + ro);
        Bm[kf] = *(const bf16x8*)(Bp + 8192 + ro);
        Bl[kf] = *(const bf16x8*)(Bp + 16384 + ro);
      }
#pragma unroll
      for (int n = 0; n < 2; ++n)
#pragma unroll
        for (int kf = 0; kf < 2; ++kf) {
          f32x4 a = acc[n][kf];
          a = MFMA(Ah[n][dci], Bh[kf], a);
          a = MFMA(Ah[n][dci], Bm[kf], a);
          a = MFMA(Am[n][dci], Bh[kf], a);
          a = MFMA(Ah[n][dci], Bl[kf], a);
          a = MFMA(Al[n][dci], Bh[kf], a);
          a = MFMA(Am[n][dci], Bm[kf], a);
          acc[n][kf] = a;
        }
    }

    // argmin update: dist = ee - 2*x.e ; codes ascending -> strict < = first occurrence
#pragma unroll
    for (int kf = 0; kf < 2; ++kf) {
      const int code = kt + kf * 16 + c;
      const float eev = ee_sh[code];
#pragma unroll
      for (int n = 0; n < 2; ++n)
#pragma unroll
        for (int r = 0; r < 4; ++r) {
          float dist = eev - acc[n][kf][r];
          if (dist < bv[n][r]) { bv[n][r] = dist; bi[n][r] = code; }
        }
    }
    __syncthreads();
  }

  // --- cross-lane argmin over the 16 code-cols (tie -> smaller idx) ---
#pragma unroll
  for (int m = 1; m <= 8; m <<= 1)
#pragma unroll
    for (int n = 0; n < 2; ++n)
#pragma unroll
      for (int r = 0; r < 4; ++r) {
        float ov = __shfl_xor(bv[n][r], m, 64);
        int   oi = __shfl_xor(bi[n][r], m, 64);
        if (ov < bv[n][r] || (ov == bv[n][r] && oi < bi[n][r])) {
          bv[n][r] = ov; bi[n][r] = oi;
        }
      }
  if (c == 0) {
#pragma unroll
    for (int n = 0; n < 2; ++n)
#pragma unroll
      for (int r = 0; r < 4; ++r)
        midx[w * 32 + n * 16 + q * 4 + r] = bi[n][r];
  }
  __syncthreads();

  if (tid < BT) {
    int ki = midx[tid];
    out_idx[(size_t)b * T_FULL + t0 + tid] = (float)ki;
    atomicAdd(&counts[ki], 1u);
  }

  // --- register epilogue: q from cb gather, x from A-regs (h+m+l), loss + stores ---
  float lsum = 0.f;
#pragma unroll
  for (int n = 0; n < 2; ++n) {
    const int tn = w * 32 + n * 16 + c;             // this lane's token
    const int kq = midx[tn];
    const float* crow = cb + (size_t)kq * D;
    float* qbase = out_q + (size_t)b * D * T_FULL + t0 + tn;
#pragma unroll
    for (int dci = 0; dci < 4; ++dci) {
      const int dcg = (dci + w) & 3;
      const int d0 = dcg * 32 + q * 8;
      float4 qa = *(const float4*)(crow + d0);
      float4 qb = *(const float4*)(crow + d0 + 4);
      float qv[8] = {qa.x, qa.y, qa.z, qa.w, qb.x, qb.y, qb.z, qb.w};
#pragma unroll
      for (int j = 0; j < 8; ++j) {
        float x = (float)Ah[n][dci][j] + (float)Am[n][dci][j] + (float)Al[n][dci][j];
        float df = qv[j] - x;
        lsum = fmaf(df, df, lsum);
        qbase[(size_t)(d0 + j) * T_FULL] = qv[j];
      }
    }
  }
#pragma unroll
  for (int o = 32; o > 0; o >>= 1) lsum += __shfl_down(lsum, o, 64);
  if (lane == 0) lred[w] = lsum;
  __syncthreads();
  if (tid == 0) {
    atomicAdd(loss_acc, lred[0] + lred[1] + lred[2] + lred[3]);
    __threadfence();                                   // publish stores + atomics
    unsigned ticket = atomicAdd(done, 1u);
    lastf = (ticket == NBLK - 1) ? 1 : 0;
  }
  __syncthreads();

  // --- last block: finalize loss + perplexity ---
  if (lastf) {
    __threadfence();
    float ent = 0.f;
#pragma unroll
    for (int i = tid; i < K; i += 256) {
      float cnt = (float)atomicAdd(&counts[i], 0u);    // coherent read
      float p = cnt * (1.0f / (float)NVEC);
      ent = fmaf(p, logf(p + 1e-10f), ent);
    }
#pragma unroll
    for (int o = 32; o > 0; o >>= 1) ent += __shfl_down(ent, o, 64);
    if (lane == 0) lred[w] = ent;
    __syncthreads();
    if (tid == 0) {
      float e = lred[0] + lred[1] + lred[2] + lred[3];
      float l = atomicAdd(loss_acc, 0.f);
      out[0]       = 0.25f * (l / (float)BDT);
      out[1 + BDT] = expf(-e);
    }
  }
}

extern "C" void kernel_launch(void* const* d_in, const int* in_sizes, int n_in,
                              void* d_out, int out_size, void* d_ws, size_t ws_size,
                              hipStream_t stream) {
  const float* inp = (const float*)d_in[0];   // [16,128,4096] fp32
  const float* cb  = (const float*)d_in[1];   // [1024,128] fp32
  float* out = (float*)d_out;                 // [loss | q(BDT) | perp | idx(B*T)]

  char* ws = (char*)d_ws;
  unsigned int* counts  = (unsigned int*)ws;                // 4 KB
  unsigned int* done    = (unsigned int*)(ws + 4096);
  float*        lossacc = (float*)(ws + 4160);
  float*        ee      = (float*)(ws + 8192);              // 4 KB
  ushort_t*     Eh      = (ushort_t*)(ws + 12288);          // 3 x 256 KB contiguous
  ushort_t*     Em      = (ushort_t*)(ws + 12288 + PLANE_B);
  ushort_t*     El      = (ushort_t*)(ws + 12288 + 2 * PLANE_B);

  prep_kernel<<<K, 128, 0, stream>>>(cb, ee, Eh, Em, El, counts, done, lossacc);
  vq_main<<<NBLK, 256, 0, stream>>>(inp, cb, ee, Eh, counts, done, lossacc, out);
}